// Round 8
// baseline (203.537 us; speedup 1.0000x reference)
//
#include <hip/hip_runtime.h>
#include <hip/hip_fp16.h>

#define BATCH 2
#define NCTX  2048
#define WIDTH 1024
#define HEADS 16
#define CH    64
#define QKVD  (3 * WIDTH)
#define MROWS (BATCH * NCTX)

typedef __attribute__((ext_vector_type(4))) float    f32x4;
typedef __attribute__((ext_vector_type(8))) _Float16 f16x8;
typedef __attribute__((ext_vector_type(4))) _Float16 f16x4;

// 0.125 (= softmax scale^2) * log2(e), folded into Q so P = exp2(S')
#define QSCALE 0.18033688011112042f

// pack two f32 -> two f16 (RTZ) as one 32-bit word
__device__ __forceinline__ unsigned pkrtz(float a, float b) {
    auto p = __builtin_amdgcn_cvt_pkrtz(a, b);
    return __builtin_bit_cast(unsigned, p);
}

// ===========================================================================
// split x [4096][1024] f32 -> f16 tiles [mb 32][kt 32][q 4][m 128][8]
// ===========================================================================
__global__ __launch_bounds__(256)
void split_x_f16(const float* __restrict__ x, __half* __restrict__ tiles)
{
    const int mb = blockIdx.x, kt = blockIdx.y;
    const int t = threadIdx.x;
    __half* tb = (__half*)tiles + ((size_t)mb * 32 + kt) * 4096;
    #pragma unroll
    for (int it = 0; it < 2; ++it) {
        const int idx = it * 256 + t;       // 512 cells (m, q)
        const int m = idx >> 2, q = idx & 3;
        const float* src = x + (size_t)(mb * 128 + m) * WIDTH + kt * 32 + q * 8;
        const f32x4 v0 = *(const f32x4*)src;
        const f32x4 v1 = *(const f32x4*)(src + 4);
        f16x8 h;
        #pragma unroll
        for (int j = 0; j < 4; ++j) { h[j] = (_Float16)v0[j]; h[4 + j] = (_Float16)v1[j]; }
        *(f16x8*)&tb[(q * 128 + m) * 8] = h;
    }
}

// ===========================================================================
// split+transpose w [K=1024][N] f32 -> f16 tiles [nb][kt 32][q 4][n 128][8]
// ===========================================================================
__global__ __launch_bounds__(256)
void split_w_f16(const float* __restrict__ w, __half* __restrict__ tiles, int N)
{
    __shared__ float tile[32][129];
    const int nb = blockIdx.x, kt = blockIdx.y;
    const int t = threadIdx.x;
    #pragma unroll
    for (int it = 0; it < 2; ++it) {
        const int idx = it * 256 + t;       // 512 x 8 floats
        const int kk = idx >> 4, n8 = idx & 15;
        const float* src = w + (size_t)(kt * 32 + kk) * N + nb * 128 + n8 * 8;
        #pragma unroll
        for (int j = 0; j < 8; ++j) tile[kk][n8 * 8 + j] = src[j];
    }
    __syncthreads();
    __half* tb = tiles + ((size_t)nb * 32 + kt) * 4096;
    #pragma unroll
    for (int it = 0; it < 2; ++it) {
        const int idx = it * 256 + t;       // 512 cells (q, nn)
        const int q = idx >> 7, nn = idx & 127;
        f16x8 h;
        #pragma unroll
        for (int j = 0; j < 8; ++j) h[j] = (_Float16)tile[q * 8 + j][nn];
        *(f16x8*)&tb[(q * 128 + nn) * 8] = h;
    }
}

// ===========================================================================
// QKV GEMM: 128x128x32 fp16 MFMA, register-prefetch + LDS double-buffer,
// one barrier per K-iter. Epilogue scatters Q (scaled by QSCALE), K, V^T.
// ===========================================================================
__global__ __launch_bounds__(256)
void gemm_qkv(const __half* __restrict__ At, const __half* __restrict__ Bt,
              const float* __restrict__ bias,
              __half* __restrict__ qg, __half* __restrict__ kg, __half* __restrict__ vtg)
{
    __shared__ __align__(16) _Float16 sm[16384];    // 2 buffers x (A 4096 | B 4096)
    const int t = threadIdx.x, lane = t & 63, w = t >> 6;
    const int lq = lane & 15, quad = lane >> 4;
    const int nb = blockIdx.x, mb = blockIdx.y;
    const int wm = (w >> 1) * 64, wn = (w & 1) * 64;

    const __half* Ab = At + ((size_t)mb * 32) * 4096;
    const __half* Bb = Bt + ((size_t)nb * 32) * 4096;
    const int c0 = w * 4;

    f32x4 acc[4][4];
    #pragma unroll
    for (int i = 0; i < 4; ++i)
        #pragma unroll
        for (int j = 0; j < 4; ++j) acc[i][j] = 0;

    f16x8 pf[4];
    #pragma unroll
    for (int i = 0; i < 4; ++i) {
        const int c = c0 + i;
        const __half* g = (c < 8 ? Ab + c * 512 : Bb + (c - 8) * 512) + lane * 8;
        pf[i] = *(const f16x8*)g;
    }
    #pragma unroll
    for (int i = 0; i < 4; ++i)
        *(f16x8*)&sm[(c0 + i) * 512 + lane * 8] = pf[i];
    __syncthreads();

    for (int kt = 0; kt < 32; ++kt) {
        _Float16* cur = sm + (kt & 1) * 8192;

        if (kt + 1 < 32) {
            #pragma unroll
            for (int i = 0; i < 4; ++i) {
                const int c = c0 + i;
                const __half* g = (c < 8 ? Ab + (size_t)(kt + 1) * 4096 + c * 512
                                         : Bb + (size_t)(kt + 1) * 4096 + (c - 8) * 512) + lane * 8;
                pf[i] = *(const f16x8*)g;
            }
        }

        f16x8 a[4], b[4];
        #pragma unroll
        for (int i = 0; i < 4; ++i) {
            a[i] = *(const f16x8*)&cur[(quad * 128 + wm + i * 16 + lq) * 8];
            b[i] = *(const f16x8*)&cur[4096 + (quad * 128 + wn + i * 16 + lq) * 8];
        }
        #pragma unroll
        for (int i = 0; i < 4; ++i)
            #pragma unroll
            for (int j = 0; j < 4; ++j)
                acc[i][j] = __builtin_amdgcn_mfma_f32_16x16x32_f16(a[i], b[j], acc[i][j], 0, 0, 0);

        if (kt + 1 < 32) {
            #pragma unroll
            for (int i = 0; i < 4; ++i)
                *(f16x8*)&sm[((kt + 1) & 1) * 8192 + (c0 + i) * 512 + lane * 8] = pf[i];
        }
        __syncthreads();
    }

    const int bb = mb >> 4;
    #pragma unroll
    for (int jf = 0; jf < 4; ++jf) {
        const int col = nb * 128 + wn + jf * 16 + lq;
        const int h = col / 192;
        const int sect = col - h * 192;
        const int type = sect >> 6;
        const int c = sect & 63;
        const float bv = bias[col];
        const size_t bh = (size_t)bb * 16 + h;
        #pragma unroll
        for (int i = 0; i < 4; ++i) {
            #pragma unroll
            for (int r = 0; r < 4; ++r) {
                const int n = (mb & 15) * 128 + wm + i * 16 + quad * 4 + r;
                const float v = acc[i][jf][r] + bv;
                if (type == 0) {
                    const size_t a2 = ((bh * 16 + (n >> 7)) * 8 + (c >> 3)) * 1024
                                      + (size_t)(n & 127) * 8 + (c & 7);
                    qg[a2] = __float2half(v * QSCALE);
                } else if (type == 1) {
                    const size_t a2 = ((bh * 32 + (n >> 6)) * 8 + (c >> 3)) * 512
                                      + (size_t)(n & 63) * 8 + (c & 7);
                    kg[a2] = __float2half(v);
                } else {
                    const size_t a2 = ((bh * 32 + (n >> 6)) * 8 + ((n >> 3) & 7)) * 512
                                      + (size_t)c * 8 + (n & 7);
                    vtg[a2] = __float2half(v);
                }
            }
        }
    }
}

// ===========================================================================
// Attention v11 = v10 with 32-q blocks (qn=2) to fit the <=128-reg tier:
// O[2][4]=32 + aq[2][2]=16 + K/V cur+pf 32 + misc ~= 108 regs ->
// __launch_bounds__(256,4) gives 4 waves/SIMD (vs 2) for the free-running
// dependency chain (S^T -> exp2 -> PV).  Grid 2048.  One-barrier epilogue:
// wave w owns (q-tile w>>1, jc-pair w&1); 24KB ship + own-sum + store.
// Zero-LDS main loop, l on VALU + shfl reduce, setprio around MFMA cluster.
// ===========================================================================
__global__ __launch_bounds__(256, 4)
void attn_mfma11(const __half* __restrict__ qg, const __half* __restrict__ kg,
                 const __half* __restrict__ vtg, __half* __restrict__ a2)
{
    __shared__ __align__(16) float red[2][2][3][2][16][16]; // 24 KB [tile][jcp][src][jj][lq][q]
    __shared__ __align__(16) float rol2[2][4][16];          // 512 B [tile][wave][lq]

    const int t = threadIdx.x, lane = t & 63, w = t >> 6;
    const int lq = lane & 15, quad = lane >> 4;
    const int bid = blockIdx.x;
    // XCD swizzle: bid&7 selects bh mod 8 -> all 64 q-tiles of a bh on one XCD.
    const int qt = (bid >> 3) & 63;                  // 32-row q tile [0,64)
    const int bh_ = (bid & 7) + ((bid >> 9) << 3);
    const size_t bh = (size_t)bh_;
    const int h = bh_ & 15, b = bh_ >> 4;

    const __half* qtile = qg + (bh * 16 + (qt >> 2)) * 8192;
    const __half* kbase = kg + bh * 32 * 4096;
    const __half* vbase = vtg + bh * 32 * 4096;

    // ---- Q fragments, direct global->reg: aq[qn][ks] = Q^T[ch][q] ----
    const int qrow0 = (qt & 3) * 32;
    f16x8 aq[2][2];
    #pragma unroll
    for (int qn = 0; qn < 2; ++qn)
        #pragma unroll
        for (int ks = 0; ks < 2; ++ks)
            aq[qn][ks] = *(const f16x8*)(qtile + (size_t)(ks * 4 + quad) * 1024
                                         + (qrow0 + qn * 16 + lq) * 8);

    // ---- per-lane K/V offsets within a kt tile (in halves) ----
    const int kofs0 = ((0 * 4 + quad) * 64 + w * 16 + lq) * 8;
    const int kofs1 = ((1 * 4 + quad) * 64 + w * 16 + lq) * 8;
    int vofs[4];
    #pragma unroll
    for (int jc = 0; jc < 4; ++jc)
        vofs[jc] = ((w * 2 + (quad >> 1)) * 64 + jc * 16 + lq) * 8 + (quad & 1) * 4;

    f32x4 O[2][4];
    float ls[2];
    #pragma unroll
    for (int qn = 0; qn < 2; ++qn) {
        ls[qn] = 0.0f;
        #pragma unroll
        for (int jc = 0; jc < 4; ++jc) O[qn][jc] = 0;
    }
    const f32x4 zc = {0.0f, 0.0f, 0.0f, 0.0f};

    // ---- prologue: load tile 0 ----
    f16x8 kf0 = *(const f16x8*)(kbase + kofs0);
    f16x8 kf1 = *(const f16x8*)(kbase + kofs1);
    f16x4 vf[4];
    #pragma unroll
    for (int jc = 0; jc < 4; ++jc) vf[jc] = *(const f16x4*)(vbase + vofs[jc]);

    const __half* kp = kbase + 4096;
    const __half* vp = vbase + 4096;

    for (int kt = 0; kt < 32; ++kt) {
        // prefetch tile kt+1 (wave-private, no sharing, no LDS)
        f16x8 kn0, kn1; f16x4 vn[4];
        if (kt < 31) {
            kn0 = *(const f16x8*)(kp + kofs0);
            kn1 = *(const f16x8*)(kp + kofs1);
            #pragma unroll
            for (int jc = 0; jc < 4; ++jc) vn[jc] = *(const f16x4*)(vp + vofs[jc]);
            kp += 4096; vp += 4096;
        }

        __builtin_amdgcn_s_setprio(1);
        #pragma unroll
        for (int qn = 0; qn < 2; ++qn) {
            // S^T: D[key16][q16] over ch=64 (2 x K=32 MFMA)
            f32x4 st = __builtin_amdgcn_mfma_f32_16x16x32_f16(kf0, aq[qn][0], zc, 0, 0, 0);
            st = __builtin_amdgcn_mfma_f32_16x16x32_f16(kf1, aq[qn][1], st, 0, 0, 0);
            // P = exp2(S'), pack to f16x4 == PV A-fragment (k=quad*4+r, row=lq)
            const float e0 = __builtin_amdgcn_exp2f(st[0]);
            const float e1 = __builtin_amdgcn_exp2f(st[1]);
            const float e2 = __builtin_amdgcn_exp2f(st[2]);
            const float e3 = __builtin_amdgcn_exp2f(st[3]);
            ls[qn] += (e0 + e1) + (e2 + e3);     // l partial on VALU pipe
            uint2 pk;
            pk.x = pkrtz(e0, e1);
            pk.y = pkrtz(e2, e3);
            const f16x4 pa = __builtin_bit_cast(f16x4, pk);
            // O += P^T x V   (all register-resident)
            #pragma unroll
            for (int jc = 0; jc < 4; ++jc)
                O[qn][jc] = __builtin_amdgcn_mfma_f32_16x16x16f16(pa, vf[jc], O[qn][jc], 0, 0, 0);
        }
        __builtin_amdgcn_s_setprio(0);

        if (kt < 31) {
            kf0 = kn0; kf1 = kn1;
            #pragma unroll
            for (int jc = 0; jc < 4; ++jc) vf[jc] = vn[jc];
        }
    }

    // ---- wave-reduce l over the 4 quad-lanes (same lq) ----
    float lsw[2];
    #pragma unroll
    for (int qn = 0; qn < 2; ++qn) {
        float v = ls[qn];
        v += __shfl_xor(v, 16, 64);
        v += __shfl_xor(v, 32, 64);
        lsw[qn] = v;
    }

    // ---- epilogue (one barrier): ship partials for non-owned slots ----
    // slot (tile t2, jc-pair p) owned by wave ow = t2*2 + p.
    #pragma unroll
    for (int t2 = 0; t2 < 2; ++t2) {
        if (quad == 0)
            rol2[t2][w][lq] = lsw[t2];
        #pragma unroll
        for (int p = 0; p < 2; ++p) {
            const int ow = t2 * 2 + p;
            if (ow != w) {                        // wave-uniform branch
                const int rel = (w < ow) ? w : w - 1;
                *(f32x4*)&red[t2][p][rel][0][lq][quad * 4] = O[t2][p * 2];
                *(f32x4*)&red[t2][p][rel][1][lq][quad * 4] = O[t2][p * 2 + 1];
            }
        }
    }
    __syncthreads();

    // ---- owner: sum l + own slot's two jc tiles, normalize, store ----
    float linv[4];
    f32x4 s0 = zc, s1 = zc;
    #pragma unroll
    for (int t2 = 0; t2 < 2; ++t2) {
        #pragma unroll
        for (int p = 0; p < 2; ++p) {
            if (t2 * 2 + p == w) {                // wave-uniform
                f32x4 lt = zc;
                #pragma unroll
                for (int w2 = 0; w2 < 4; ++w2)
                    lt += *(const f32x4*)&rol2[t2][w2][quad * 4];
                #pragma unroll
                for (int r = 0; r < 4; ++r) linv[r] = 1.0f / lt[r];
                s0 = O[t2][p * 2];
                s1 = O[t2][p * 2 + 1];
                #pragma unroll
                for (int src = 0; src < 3; ++src) {
                    s0 += *(const f32x4*)&red[t2][p][src][0][lq][quad * 4];
                    s1 += *(const f32x4*)&red[t2][p][src][1][lq][quad * 4];
                }
            }
        }
    }

    __half* a2t = a2 + ((size_t)(b * 16 + (qt >> 2)) * 32) * 4096;
    const int mb0 = (qt & 3) * 32 + (w >> 1) * 16 + quad * 4;
    const int jc0 = (w & 1) * 2;

    {
        const int ch0 = h * 64 + (jc0 + 0) * 16 + lq;
        const int ktp0 = ch0 >> 5, qc0 = (ch0 >> 3) & 3, j0 = ch0 & 7;
        #pragma unroll
        for (int r = 0; r < 4; ++r)
            a2t[(size_t)ktp0 * 4096 + (qc0 * 128 + mb0 + r) * 8 + j0] =
                __float2half(s0[r] * linv[r]);
        const int ch1 = h * 64 + (jc0 + 1) * 16 + lq;
        const int ktp1 = ch1 >> 5, qc1 = (ch1 >> 3) & 3, j1 = ch1 & 7;
        #pragma unroll
        for (int r = 0; r < 4; ++r)
            a2t[(size_t)ktp1 * 4096 + (qc1 * 128 + mb0 + r) * 8 + j1] =
                __float2half(s1[r] * linv[r]);
    }
}

// ===========================================================================
// Proj GEMM: out = attn @ w_proj + b. Prefetch + double-buffer (reg-staged).
// ===========================================================================
__global__ __launch_bounds__(256)
void gemm_proj(const __half* __restrict__ At, const __half* __restrict__ Bt,
               const float* __restrict__ bias, float* __restrict__ out)
{
    __shared__ __align__(16) _Float16 sm[16384];
    const int t = threadIdx.x, lane = t & 63, w = t >> 6;
    const int lq = lane & 15, quad = lane >> 4;
    const int nb = blockIdx.x, mb = blockIdx.y;
    const int wm = (w >> 1) * 64, wn = (w & 1) * 64;

    const __half* Ab = At + ((size_t)mb * 32) * 4096;
    const __half* Bb = Bt + ((size_t)nb * 32) * 4096;
    const int c0 = w * 4;

    f32x4 acc[4][4];
    #pragma unroll
    for (int i = 0; i < 4; ++i)
        #pragma unroll
        for (int j = 0; j < 4; ++j) acc[i][j] = 0;

    f16x8 pf[4];
    #pragma unroll
    for (int i = 0; i < 4; ++i) {
        const int c = c0 + i;
        const __half* g = (c < 8 ? Ab + c * 512 : Bb + (c - 8) * 512) + lane * 8;
        pf[i] = *(const f16x8*)g;
    }
    #pragma unroll
    for (int i = 0; i < 4; ++i)
        *(f16x8*)&sm[(c0 + i) * 512 + lane * 8] = pf[i];
    __syncthreads();

    for (int kt = 0; kt < 32; ++kt) {
        _Float16* cur = sm + (kt & 1) * 8192;

        if (kt + 1 < 32) {
            #pragma unroll
            for (int i = 0; i < 4; ++i) {
                const int c = c0 + i;
                const __half* g = (c < 8 ? Ab + (size_t)(kt + 1) * 4096 + c * 512
                                         : Bb + (size_t)(kt + 1) * 4096 + (c - 8) * 512) + lane * 8;
                pf[i] = *(const f16x8*)g;
            }
        }

        f16x8 a[4], b[4];
        #pragma unroll
        for (int i = 0; i < 4; ++i) {
            a[i] = *(const f16x8*)&cur[(quad * 128 + wm + i * 16 + lq) * 8];
            b[i] = *(const f16x8*)&cur[4096 + (quad * 128 + wn + i * 16 + lq) * 8];
        }
        #pragma unroll
        for (int i = 0; i < 4; ++i)
            #pragma unroll
            for (int j = 0; j < 4; ++j)
                acc[i][j] = __builtin_amdgcn_mfma_f32_16x16x32_f16(a[i], b[j], acc[i][j], 0, 0, 0);

        if (kt + 1 < 32) {
            #pragma unroll
            for (int i = 0; i < 4; ++i)
                *(f16x8*)&sm[((kt + 1) & 1) * 8192 + (c0 + i) * 512 + lane * 8] = pf[i];
        }
        __syncthreads();
    }

    #pragma unroll
    for (int jf = 0; jf < 4; ++jf) {
        const int col = nb * 128 + wn + jf * 16 + lq;
        const float bv = bias[col];
        #pragma unroll
        for (int i = 0; i < 4; ++i)
            #pragma unroll
            for (int r = 0; r < 4; ++r) {
                const int row = mb * 128 + wm + i * 16 + quad * 4 + r;
                out[(size_t)row * WIDTH + col] = acc[i][jf][r] + bv;
            }
    }
}

// ===========================================================================
extern "C" void kernel_launch(void* const* d_in, const int* in_sizes, int n_in,
                              void* d_out, int out_size, void* d_ws, size_t ws_size,
                              hipStream_t stream)
{
    const float* x      = (const float*)d_in[0];
    const float* w_qkv  = (const float*)d_in[1];
    const float* b_qkv  = (const float*)d_in[2];
    const float* w_proj = (const float*)d_in[3];
    const float* b_proj = (const float*)d_in[4];
    float* out = (float*)d_out;

    char* p = (char*)d_ws;
    size_t o = 0;
    __half* A1  = (__half*)(p + o); o += (size_t)MROWS * WIDTH * 2;
    __half* Bq  = (__half*)(p + o); o += (size_t)WIDTH * QKVD * 2;
    __half* Qg  = (__half*)(p + o); o += (size_t)MROWS * WIDTH * 2;
    __half* Kg  = (__half*)(p + o); o += (size_t)MROWS * WIDTH * 2;
    __half* Vtg = (__half*)(p + o); o += (size_t)MROWS * WIDTH * 2;
    __half* A2  = (__half*)(p + o); o += (size_t)MROWS * WIDTH * 2;
    __half* Bp  = (__half*)(p + o); o += (size_t)WIDTH * WIDTH * 2;

    dim3 blk(256);

    split_x_f16<<<dim3(32, 32), blk, 0, stream>>>(x, A1);
    split_w_f16<<<dim3(24, 32), blk, 0, stream>>>(w_qkv, Bq, QKVD);
    split_w_f16<<<dim3(8, 32),  blk, 0, stream>>>(w_proj, Bp, WIDTH);

    gemm_qkv<<<dim3(24, 32), blk, 0, stream>>>(A1, Bq, b_qkv, Qg, Kg, Vtg);

    attn_mfma11<<<dim3(2048), blk, 0, stream>>>(Qg, Kg, Vtg, A2);

    gemm_proj<<<dim3(8, 32), blk, 0, stream>>>(A2, Bp, b_proj, out);
}

// Round 9
// 194.853 us; speedup vs baseline: 1.0446x; 1.0446x over previous
//
#include <hip/hip_runtime.h>
#include <hip/hip_fp16.h>

#define BATCH 2
#define NCTX  2048
#define WIDTH 1024
#define HEADS 16
#define CH    64
#define QKVD  (3 * WIDTH)
#define MROWS (BATCH * NCTX)

typedef __attribute__((ext_vector_type(4))) float    f32x4;
typedef __attribute__((ext_vector_type(8))) _Float16 f16x8;
typedef __attribute__((ext_vector_type(4))) _Float16 f16x4;

// 0.125 (= softmax scale^2) * log2(e), folded into Q so P = exp2(S')
#define QSCALE 0.18033688011112042f

// pack two f32 -> two f16 (RTZ) as one 32-bit word
__device__ __forceinline__ unsigned pkrtz(float a, float b) {
    auto p = __builtin_amdgcn_cvt_pkrtz(a, b);
    return __builtin_bit_cast(unsigned, p);
}

// ===========================================================================
// Fused split: one launch covers
//   bid [0,1024):    x [4096][1024] f32 -> A1 tiles [mb 32][kt 32][4096]
//   bid [1024,1792): w_qkv -> Bq tiles (transpose), N=3072
//   bid [1792,2048): w_proj -> Bp tiles (transpose), N=1024
// ===========================================================================
__global__ __launch_bounds__(256)
void split_all(const float* __restrict__ x,
               const float* __restrict__ w_qkv, const float* __restrict__ w_proj,
               __half* __restrict__ A1, __half* __restrict__ Bq, __half* __restrict__ Bp)
{
    __shared__ float tile[32][129];
    const int bid = blockIdx.x;
    const int t = threadIdx.x;

    if (bid < 1024) {
        const int mb = bid >> 5, kt = bid & 31;
        __half* tb = A1 + ((size_t)mb * 32 + kt) * 4096;
        #pragma unroll
        for (int it = 0; it < 2; ++it) {
            const int idx = it * 256 + t;       // 512 cells (m, q)
            const int m = idx >> 2, q = idx & 3;
            const float* src = x + (size_t)(mb * 128 + m) * WIDTH + kt * 32 + q * 8;
            const f32x4 v0 = *(const f32x4*)src;
            const f32x4 v1 = *(const f32x4*)(src + 4);
            f16x8 h;
            #pragma unroll
            for (int j = 0; j < 4; ++j) { h[j] = (_Float16)v0[j]; h[4 + j] = (_Float16)v1[j]; }
            *(f16x8*)&tb[(q * 128 + m) * 8] = h;
        }
        return;
    }

    const float* w; __half* tiles; int N, nb, kt;
    if (bid < 1792) {
        const int u = bid - 1024;
        w = w_qkv; tiles = Bq; N = QKVD; nb = u >> 5; kt = u & 31;
    } else {
        const int u = bid - 1792;
        w = w_proj; tiles = Bp; N = WIDTH; nb = u >> 5; kt = u & 31;
    }

    #pragma unroll
    for (int it = 0; it < 2; ++it) {
        const int idx = it * 256 + t;       // 512 x 8 floats
        const int kk = idx >> 4, n8 = idx & 15;
        const float* src = w + (size_t)(kt * 32 + kk) * N + nb * 128 + n8 * 8;
        #pragma unroll
        for (int j = 0; j < 8; ++j) tile[kk][n8 * 8 + j] = src[j];
    }
    __syncthreads();
    __half* tb = tiles + ((size_t)nb * 32 + kt) * 4096;
    #pragma unroll
    for (int it = 0; it < 2; ++it) {
        const int idx = it * 256 + t;       // 512 cells (q, nn)
        const int q = idx >> 7, nn = idx & 127;
        f16x8 h;
        #pragma unroll
        for (int j = 0; j < 8; ++j) h[j] = (_Float16)tile[q * 8 + j][nn];
        *(f16x8*)&tb[(q * 128 + nn) * 8] = h;
    }
}

// ===========================================================================
// QKV GEMM: 128x128x32 fp16 MFMA, register-prefetch + LDS double-buffer,
// one barrier per K-iter. Epilogue scatters Q (scaled by QSCALE), K, V^T.
// ===========================================================================
__global__ __launch_bounds__(256)
void gemm_qkv(const __half* __restrict__ At, const __half* __restrict__ Bt,
              const float* __restrict__ bias,
              __half* __restrict__ qg, __half* __restrict__ kg, __half* __restrict__ vtg)
{
    __shared__ __align__(16) _Float16 sm[16384];    // 2 buffers x (A 4096 | B 4096)
    const int t = threadIdx.x, lane = t & 63, w = t >> 6;
    const int lq = lane & 15, quad = lane >> 4;
    const int nb = blockIdx.x, mb = blockIdx.y;
    const int wm = (w >> 1) * 64, wn = (w & 1) * 64;

    const __half* Ab = At + ((size_t)mb * 32) * 4096;
    const __half* Bb = Bt + ((size_t)nb * 32) * 4096;
    const int c0 = w * 4;

    f32x4 acc[4][4];
    #pragma unroll
    for (int i = 0; i < 4; ++i)
        #pragma unroll
        for (int j = 0; j < 4; ++j) acc[i][j] = 0;

    f16x8 pf[4];
    #pragma unroll
    for (int i = 0; i < 4; ++i) {
        const int c = c0 + i;
        const __half* g = (c < 8 ? Ab + c * 512 : Bb + (c - 8) * 512) + lane * 8;
        pf[i] = *(const f16x8*)g;
    }
    #pragma unroll
    for (int i = 0; i < 4; ++i)
        *(f16x8*)&sm[(c0 + i) * 512 + lane * 8] = pf[i];
    __syncthreads();

    for (int kt = 0; kt < 32; ++kt) {
        _Float16* cur = sm + (kt & 1) * 8192;

        if (kt + 1 < 32) {
            #pragma unroll
            for (int i = 0; i < 4; ++i) {
                const int c = c0 + i;
                const __half* g = (c < 8 ? Ab + (size_t)(kt + 1) * 4096 + c * 512
                                         : Bb + (size_t)(kt + 1) * 4096 + (c - 8) * 512) + lane * 8;
                pf[i] = *(const f16x8*)g;
            }
        }

        f16x8 a[4], b[4];
        #pragma unroll
        for (int i = 0; i < 4; ++i) {
            a[i] = *(const f16x8*)&cur[(quad * 128 + wm + i * 16 + lq) * 8];
            b[i] = *(const f16x8*)&cur[4096 + (quad * 128 + wn + i * 16 + lq) * 8];
        }
        #pragma unroll
        for (int i = 0; i < 4; ++i)
            #pragma unroll
            for (int j = 0; j < 4; ++j)
                acc[i][j] = __builtin_amdgcn_mfma_f32_16x16x32_f16(a[i], b[j], acc[i][j], 0, 0, 0);

        if (kt + 1 < 32) {
            #pragma unroll
            for (int i = 0; i < 4; ++i)
                *(f16x8*)&sm[((kt + 1) & 1) * 8192 + (c0 + i) * 512 + lane * 8] = pf[i];
        }
        __syncthreads();
    }

    const int bb = mb >> 4;
    #pragma unroll
    for (int jf = 0; jf < 4; ++jf) {
        const int col = nb * 128 + wn + jf * 16 + lq;
        const int h = col / 192;
        const int sect = col - h * 192;
        const int type = sect >> 6;
        const int c = sect & 63;
        const float bv = bias[col];
        const size_t bh = (size_t)bb * 16 + h;
        #pragma unroll
        for (int i = 0; i < 4; ++i) {
            #pragma unroll
            for (int r = 0; r < 4; ++r) {
                const int n = (mb & 15) * 128 + wm + i * 16 + quad * 4 + r;
                const float v = acc[i][jf][r] + bv;
                if (type == 0) {
                    const size_t a2 = ((bh * 16 + (n >> 7)) * 8 + (c >> 3)) * 1024
                                      + (size_t)(n & 127) * 8 + (c & 7);
                    qg[a2] = __float2half(v * QSCALE);
                } else if (type == 1) {
                    const size_t a2 = ((bh * 32 + (n >> 6)) * 8 + (c >> 3)) * 512
                                      + (size_t)(n & 63) * 8 + (c & 7);
                    kg[a2] = __float2half(v);
                } else {
                    const size_t a2 = ((bh * 32 + (n >> 6)) * 8 + ((n >> 3) & 7)) * 512
                                      + (size_t)c * 8 + (n & 7);
                    vtg[a2] = __float2half(v);
                }
            }
        }
    }
}

// ===========================================================================
// Attention v10 (R7 winner, 50.8us): 64-q blocks, key-partitioned waves,
// zero-LDS main loop, P register-resident, l on VALU + shfl reduce,
// setprio around MFMA cluster, static register indices everywhere.
// ===========================================================================
__global__ __launch_bounds__(256, 2)
void attn_mfma10(const __half* __restrict__ qg, const __half* __restrict__ kg,
                 const __half* __restrict__ vtg, __half* __restrict__ a2)
{
    __shared__ __align__(16) float red[4][3][2][16][16];  // 24 KB: [qn][src][jj][ch][q]
    __shared__ __align__(16) float rol2[4][4][16];        // 1 KB: [qn][wave][lq] l partials

    const int t = threadIdx.x, lane = t & 63, w = t >> 6;
    const int lq = lane & 15, quad = lane >> 4;
    const int bid = blockIdx.x;
    // XCD swizzle: bid&7 selects bh mod 8 -> all 32 q-tiles of a bh on one XCD.
    const int qt = (bid >> 3) & 31;                  // 64-row q tile [0,32)
    const int bh_ = (bid & 7) + ((bid >> 8) << 3);
    const size_t bh = (size_t)bh_;
    const int h = bh_ & 15, b = bh_ >> 4;

    const __half* qtile = qg + (bh * 16 + (qt >> 1)) * 8192;
    const __half* kbase = kg + bh * 32 * 4096;
    const __half* vbase = vtg + bh * 32 * 4096;

    // ---- Q fragments, direct global->reg: aq[qn][ks] = Q^T[ch][q] ----
    const int qrow0 = (qt & 1) * 64;
    f16x8 aq[4][2];
    #pragma unroll
    for (int qn = 0; qn < 4; ++qn)
        #pragma unroll
        for (int ks = 0; ks < 2; ++ks)
            aq[qn][ks] = *(const f16x8*)(qtile + (size_t)(ks * 4 + quad) * 1024
                                         + (qrow0 + qn * 16 + lq) * 8);

    // ---- per-lane K/V offsets within a kt tile (in halves) ----
    const int kofs0 = ((0 * 4 + quad) * 64 + w * 16 + lq) * 8;
    const int kofs1 = ((1 * 4 + quad) * 64 + w * 16 + lq) * 8;
    int vofs[4];
    #pragma unroll
    for (int jc = 0; jc < 4; ++jc)
        vofs[jc] = ((w * 2 + (quad >> 1)) * 64 + jc * 16 + lq) * 8 + (quad & 1) * 4;

    f32x4 O[4][4];
    float ls[4];
    #pragma unroll
    for (int qn = 0; qn < 4; ++qn) {
        ls[qn] = 0.0f;
        #pragma unroll
        for (int jc = 0; jc < 4; ++jc) O[qn][jc] = 0;
    }
    const f32x4 zc = {0.0f, 0.0f, 0.0f, 0.0f};

    // ---- prologue: load tile 0 ----
    f16x8 kf0 = *(const f16x8*)(kbase + kofs0);
    f16x8 kf1 = *(const f16x8*)(kbase + kofs1);
    f16x4 vf[4];
    #pragma unroll
    for (int jc = 0; jc < 4; ++jc) vf[jc] = *(const f16x4*)(vbase + vofs[jc]);

    const __half* kp = kbase + 4096;
    const __half* vp = vbase + 4096;

    for (int kt = 0; kt < 32; ++kt) {
        // prefetch tile kt+1 (wave-private, no sharing, no LDS)
        f16x8 kn0, kn1; f16x4 vn[4];
        if (kt < 31) {
            kn0 = *(const f16x8*)(kp + kofs0);
            kn1 = *(const f16x8*)(kp + kofs1);
            #pragma unroll
            for (int jc = 0; jc < 4; ++jc) vn[jc] = *(const f16x4*)(vp + vofs[jc]);
            kp += 4096; vp += 4096;
        }

        __builtin_amdgcn_s_setprio(1);
        #pragma unroll
        for (int qn = 0; qn < 4; ++qn) {
            // S^T: D[key16][q16] over ch=64 (2 x K=32 MFMA)
            f32x4 st = __builtin_amdgcn_mfma_f32_16x16x32_f16(kf0, aq[qn][0], zc, 0, 0, 0);
            st = __builtin_amdgcn_mfma_f32_16x16x32_f16(kf1, aq[qn][1], st, 0, 0, 0);
            // P = exp2(S'), pack to f16x4 == PV A-fragment (k=quad*4+r, row=lq)
            const float e0 = __builtin_amdgcn_exp2f(st[0]);
            const float e1 = __builtin_amdgcn_exp2f(st[1]);
            const float e2 = __builtin_amdgcn_exp2f(st[2]);
            const float e3 = __builtin_amdgcn_exp2f(st[3]);
            ls[qn] += (e0 + e1) + (e2 + e3);     // l partial on VALU pipe
            uint2 pk;
            pk.x = pkrtz(e0, e1);
            pk.y = pkrtz(e2, e3);
            const f16x4 pa = __builtin_bit_cast(f16x4, pk);
            // O += P^T x V   (all register-resident)
            #pragma unroll
            for (int jc = 0; jc < 4; ++jc)
                O[qn][jc] = __builtin_amdgcn_mfma_f32_16x16x16f16(pa, vf[jc], O[qn][jc], 0, 0, 0);
        }
        __builtin_amdgcn_s_setprio(0);

        if (kt < 31) {
            kf0 = kn0; kf1 = kn1;
            #pragma unroll
            for (int jc = 0; jc < 4; ++jc) vf[jc] = vn[jc];
        }
    }

    // ---- wave-reduce l over the 4 quad-lanes (same lq) ----
    float lsw[4];
    #pragma unroll
    for (int qn = 0; qn < 4; ++qn) {
        float v = ls[qn];
        v += __shfl_xor(v, 16, 64);
        v += __shfl_xor(v, 32, 64);
        lsw[qn] = v;
    }

    // ---- epilogue: reduce O, l across the 4 key-slice waves via LDS ----
    #pragma unroll
    for (int qn = 0; qn < 4; ++qn) {
        if (quad == 0)
            rol2[qn][w][lq] = lsw[qn];           // 16 lanes write l[lq]
        if (qn != w) {
            const int rel = (w < qn) ? w : w - 1;
            *(f32x4*)&red[qn][rel][0][lq][quad * 4] = O[qn][0];
            *(f32x4*)&red[qn][rel][1][lq][quad * 4] = O[qn][1];
        }
    }
    __syncthreads();

    float linv[4];
    f32x4 s0 = zc, s1 = zc;
    #pragma unroll
    for (int qn = 0; qn < 4; ++qn) {
        if (qn == w) {
            f32x4 lt = zc;
            #pragma unroll
            for (int w2 = 0; w2 < 4; ++w2)
                lt += *(const f32x4*)&rol2[qn][w2][quad * 4];
            #pragma unroll
            for (int r = 0; r < 4; ++r) linv[r] = 1.0f / lt[r];
            s0 = O[qn][0];
            s1 = O[qn][1];
            #pragma unroll
            for (int src = 0; src < 3; ++src) {
                s0 += *(const f32x4*)&red[qn][src][0][lq][quad * 4];
                s1 += *(const f32x4*)&red[qn][src][1][lq][quad * 4];
            }
        }
    }

    __half* a2t = a2 + ((size_t)(b * 16 + (qt >> 1)) * 32) * 4096;
    const int mb0 = (qt & 1) * 64 + w * 16 + quad * 4;

    // store jc 0,1
    {
        const int ch0 = h * 64 + 0 * 16 + lq;
        const int ktp0 = ch0 >> 5, qc0 = (ch0 >> 3) & 3, j0 = ch0 & 7;
        #pragma unroll
        for (int r = 0; r < 4; ++r)
            a2t[(size_t)ktp0 * 4096 + (qc0 * 128 + mb0 + r) * 8 + j0] =
                __float2half(s0[r] * linv[r]);
        const int ch1 = h * 64 + 1 * 16 + lq;
        const int ktp1 = ch1 >> 5, qc1 = (ch1 >> 3) & 3, j1 = ch1 & 7;
        #pragma unroll
        for (int r = 0; r < 4; ++r)
            a2t[(size_t)ktp1 * 4096 + (qc1 * 128 + mb0 + r) * 8 + j1] =
                __float2half(s1[r] * linv[r]);
    }
    __syncthreads();

    // round 1: jc 2,3
    #pragma unroll
    for (int qn = 0; qn < 4; ++qn) {
        if (qn != w) {
            const int rel = (w < qn) ? w : w - 1;
            *(f32x4*)&red[qn][rel][0][lq][quad * 4] = O[qn][2];
            *(f32x4*)&red[qn][rel][1][lq][quad * 4] = O[qn][3];
        }
    }
    __syncthreads();

    f32x4 s2 = zc, s3 = zc;
    #pragma unroll
    for (int qn = 0; qn < 4; ++qn) {
        if (qn == w) {
            s2 = O[qn][2];
            s3 = O[qn][3];
            #pragma unroll
            for (int src = 0; src < 3; ++src) {
                s2 += *(const f32x4*)&red[qn][src][0][lq][quad * 4];
                s3 += *(const f32x4*)&red[qn][src][1][lq][quad * 4];
            }
        }
    }

    {
        const int ch2 = h * 64 + 2 * 16 + lq;
        const int ktp2 = ch2 >> 5, qc2 = (ch2 >> 3) & 3, j2 = ch2 & 7;
        #pragma unroll
        for (int r = 0; r < 4; ++r)
            a2t[(size_t)ktp2 * 4096 + (qc2 * 128 + mb0 + r) * 8 + j2] =
                __float2half(s2[r] * linv[r]);
        const int ch3 = h * 64 + 3 * 16 + lq;
        const int ktp3 = ch3 >> 5, qc3 = (ch3 >> 3) & 3, j3 = ch3 & 7;
        #pragma unroll
        for (int r = 0; r < 4; ++r)
            a2t[(size_t)ktp3 * 4096 + (qc3 * 128 + mb0 + r) * 8 + j3] =
                __float2half(s3[r] * linv[r]);
    }
}

// ===========================================================================
// Proj GEMM: out = attn @ w_proj + b.  512 threads / 8 waves per block
// (was 4): grid 256 = 1 block/CU -> 8 waves/CU = 2 waves/SIMD (was 1).
// Each wave owns a 64x32 sub-tile; staging 2 chunks/wave; same LDS layout.
// ===========================================================================
__global__ __launch_bounds__(512)
void gemm_proj(const __half* __restrict__ At, const __half* __restrict__ Bt,
               const float* __restrict__ bias, float* __restrict__ out)
{
    __shared__ __align__(16) _Float16 sm[16384];
    const int t = threadIdx.x, lane = t & 63, w = t >> 6;   // w in [0,8)
    const int lq = lane & 15, quad = lane >> 4;
    const int nb = blockIdx.x, mb = blockIdx.y;
    const int wm = (w >> 2) * 64, wn = (w & 3) * 32;

    const __half* Ab = At + ((size_t)mb * 32) * 4096;
    const __half* Bb = Bt + ((size_t)nb * 32) * 4096;
    const int c0 = w * 2;

    f32x4 acc[4][2];
    #pragma unroll
    for (int i = 0; i < 4; ++i)
        #pragma unroll
        for (int j = 0; j < 2; ++j) acc[i][j] = 0;

    f16x8 pf[2];
    #pragma unroll
    for (int i = 0; i < 2; ++i) {
        const int c = c0 + i;
        const __half* g = (c < 8 ? Ab + c * 512 : Bb + (c - 8) * 512) + lane * 8;
        pf[i] = *(const f16x8*)g;
    }
    #pragma unroll
    for (int i = 0; i < 2; ++i)
        *(f16x8*)&sm[(c0 + i) * 512 + lane * 8] = pf[i];
    __syncthreads();

    for (int kt = 0; kt < 32; ++kt) {
        _Float16* cur = sm + (kt & 1) * 8192;

        if (kt + 1 < 32) {
            #pragma unroll
            for (int i = 0; i < 2; ++i) {
                const int c = c0 + i;
                const __half* g = (c < 8 ? Ab + (size_t)(kt + 1) * 4096 + c * 512
                                         : Bb + (size_t)(kt + 1) * 4096 + (c - 8) * 512) + lane * 8;
                pf[i] = *(const f16x8*)g;
            }
        }

        f16x8 a[4], b[2];
        #pragma unroll
        for (int i = 0; i < 4; ++i)
            a[i] = *(const f16x8*)&cur[(quad * 128 + wm + i * 16 + lq) * 8];
        #pragma unroll
        for (int j = 0; j < 2; ++j)
            b[j] = *(const f16x8*)&cur[4096 + (quad * 128 + wn + j * 16 + lq) * 8];
        #pragma unroll
        for (int i = 0; i < 4; ++i)
            #pragma unroll
            for (int j = 0; j < 2; ++j)
                acc[i][j] = __builtin_amdgcn_mfma_f32_16x16x32_f16(a[i], b[j], acc[i][j], 0, 0, 0);

        if (kt + 1 < 32) {
            #pragma unroll
            for (int i = 0; i < 2; ++i)
                *(f16x8*)&sm[((kt + 1) & 1) * 8192 + (c0 + i) * 512 + lane * 8] = pf[i];
        }
        __syncthreads();
    }

    #pragma unroll
    for (int jf = 0; jf < 2; ++jf) {
        const int col = nb * 128 + wn + jf * 16 + lq;
        const float bv = bias[col];
        #pragma unroll
        for (int i = 0; i < 4; ++i)
            #pragma unroll
            for (int r = 0; r < 4; ++r) {
                const int row = mb * 128 + wm + i * 16 + quad * 4 + r;
                out[(size_t)row * WIDTH + col] = acc[i][jf][r] + bv;
            }
    }
}

// ===========================================================================
extern "C" void kernel_launch(void* const* d_in, const int* in_sizes, int n_in,
                              void* d_out, int out_size, void* d_ws, size_t ws_size,
                              hipStream_t stream)
{
    const float* x      = (const float*)d_in[0];
    const float* w_qkv  = (const float*)d_in[1];
    const float* b_qkv  = (const float*)d_in[2];
    const float* w_proj = (const float*)d_in[3];
    const float* b_proj = (const float*)d_in[4];
    float* out = (float*)d_out;

    char* p = (char*)d_ws;
    size_t o = 0;
    __half* A1  = (__half*)(p + o); o += (size_t)MROWS * WIDTH * 2;
    __half* Bq  = (__half*)(p + o); o += (size_t)WIDTH * QKVD * 2;
    __half* Qg  = (__half*)(p + o); o += (size_t)MROWS * WIDTH * 2;
    __half* Kg  = (__half*)(p + o); o += (size_t)MROWS * WIDTH * 2;
    __half* Vtg = (__half*)(p + o); o += (size_t)MROWS * WIDTH * 2;
    __half* A2  = (__half*)(p + o); o += (size_t)MROWS * WIDTH * 2;
    __half* Bp  = (__half*)(p + o); o += (size_t)WIDTH * WIDTH * 2;

    split_all<<<dim3(2048), dim3(256), 0, stream>>>(x, w_qkv, w_proj, A1, Bq, Bp);

    gemm_qkv<<<dim3(24, 32), dim3(256), 0, stream>>>(A1, Bq, b_qkv, Qg, Kg, Vtg);

    attn_mfma10<<<dim3(1024), dim3(256), 0, stream>>>(Qg, Kg, Vtg, A2);

    gemm_proj<<<dim3(8, 32), dim3(512), 0, stream>>>(A2, Bp, b_proj, out);
}

// Round 10
// 191.311 us; speedup vs baseline: 1.0639x; 1.0185x over previous
//
#include <hip/hip_runtime.h>
#include <hip/hip_fp16.h>

#define BATCH 2
#define NCTX  2048
#define WIDTH 1024
#define HEADS 16
#define CH    64
#define QKVD  (3 * WIDTH)
#define MROWS (BATCH * NCTX)

typedef __attribute__((ext_vector_type(4))) float    f32x4;
typedef __attribute__((ext_vector_type(8))) _Float16 f16x8;
typedef __attribute__((ext_vector_type(4))) _Float16 f16x4;

// 0.125 (= softmax scale^2) * log2(e), folded into Q so P = exp2(S')
#define QSCALE 0.18033688011112042f

// pack two f32 -> two f16 (RTZ) as one 32-bit word
__device__ __forceinline__ unsigned pkrtz(float a, float b) {
    auto p = __builtin_amdgcn_cvt_pkrtz(a, b);
    return __builtin_bit_cast(unsigned, p);
}

// ===========================================================================
// Fused split: one launch covers
//   bid [0,1024):    x [4096][1024] f32 -> A1 tiles [mb 32][kt 32][4096]
//   bid [1024,1792): w_qkv -> Bq tiles (transpose), N=3072
//   bid [1792,2048): w_proj -> Bp tiles (transpose), N=1024
// ===========================================================================
__global__ __launch_bounds__(256)
void split_all(const float* __restrict__ x,
               const float* __restrict__ w_qkv, const float* __restrict__ w_proj,
               __half* __restrict__ A1, __half* __restrict__ Bq, __half* __restrict__ Bp)
{
    __shared__ float tile[32][129];
    const int bid = blockIdx.x;
    const int t = threadIdx.x;

    if (bid < 1024) {
        const int mb = bid >> 5, kt = bid & 31;
        __half* tb = A1 + ((size_t)mb * 32 + kt) * 4096;
        #pragma unroll
        for (int it = 0; it < 2; ++it) {
            const int idx = it * 256 + t;       // 512 cells (m, q)
            const int m = idx >> 2, q = idx & 3;
            const float* src = x + (size_t)(mb * 128 + m) * WIDTH + kt * 32 + q * 8;
            const f32x4 v0 = *(const f32x4*)src;
            const f32x4 v1 = *(const f32x4*)(src + 4);
            f16x8 h;
            #pragma unroll
            for (int j = 0; j < 4; ++j) { h[j] = (_Float16)v0[j]; h[4 + j] = (_Float16)v1[j]; }
            *(f16x8*)&tb[(q * 128 + m) * 8] = h;
        }
        return;
    }

    const float* w; __half* tiles; int N, nb, kt;
    if (bid < 1792) {
        const int u = bid - 1024;
        w = w_qkv; tiles = Bq; N = QKVD; nb = u >> 5; kt = u & 31;
    } else {
        const int u = bid - 1792;
        w = w_proj; tiles = Bp; N = WIDTH; nb = u >> 5; kt = u & 31;
    }

    #pragma unroll
    for (int it = 0; it < 2; ++it) {
        const int idx = it * 256 + t;       // 512 x 8 floats
        const int kk = idx >> 4, n8 = idx & 15;
        const float* src = w + (size_t)(kt * 32 + kk) * N + nb * 128 + n8 * 8;
        #pragma unroll
        for (int j = 0; j < 8; ++j) tile[kk][n8 * 8 + j] = src[j];
    }
    __syncthreads();
    __half* tb = tiles + ((size_t)nb * 32 + kt) * 4096;
    #pragma unroll
    for (int it = 0; it < 2; ++it) {
        const int idx = it * 256 + t;       // 512 cells (q, nn)
        const int q = idx >> 7, nn = idx & 127;
        f16x8 h;
        #pragma unroll
        for (int j = 0; j < 8; ++j) h[j] = (_Float16)tile[q * 8 + j][nn];
        *(f16x8*)&tb[(q * 128 + nn) * 8] = h;
    }
}

// ===========================================================================
// QKV GEMM: 128x128x32 fp16 MFMA, register-prefetch + LDS double-buffer,
// one barrier per K-iter. Epilogue scatters Q (scaled by QSCALE), K, V^T.
// ===========================================================================
__global__ __launch_bounds__(256)
void gemm_qkv(const __half* __restrict__ At, const __half* __restrict__ Bt,
              const float* __restrict__ bias,
              __half* __restrict__ qg, __half* __restrict__ kg, __half* __restrict__ vtg)
{
    __shared__ __align__(16) _Float16 sm[16384];    // 2 buffers x (A 4096 | B 4096)
    const int t = threadIdx.x, lane = t & 63, w = t >> 6;
    const int lq = lane & 15, quad = lane >> 4;
    const int nb = blockIdx.x, mb = blockIdx.y;
    const int wm = (w >> 1) * 64, wn = (w & 1) * 64;

    const __half* Ab = At + ((size_t)mb * 32) * 4096;
    const __half* Bb = Bt + ((size_t)nb * 32) * 4096;
    const int c0 = w * 4;

    f32x4 acc[4][4];
    #pragma unroll
    for (int i = 0; i < 4; ++i)
        #pragma unroll
        for (int j = 0; j < 4; ++j) acc[i][j] = 0;

    f16x8 pf[4];
    #pragma unroll
    for (int i = 0; i < 4; ++i) {
        const int c = c0 + i;
        const __half* g = (c < 8 ? Ab + c * 512 : Bb + (c - 8) * 512) + lane * 8;
        pf[i] = *(const f16x8*)g;
    }
    #pragma unroll
    for (int i = 0; i < 4; ++i)
        *(f16x8*)&sm[(c0 + i) * 512 + lane * 8] = pf[i];
    __syncthreads();

    for (int kt = 0; kt < 32; ++kt) {
        _Float16* cur = sm + (kt & 1) * 8192;

        if (kt + 1 < 32) {
            #pragma unroll
            for (int i = 0; i < 4; ++i) {
                const int c = c0 + i;
                const __half* g = (c < 8 ? Ab + (size_t)(kt + 1) * 4096 + c * 512
                                         : Bb + (size_t)(kt + 1) * 4096 + (c - 8) * 512) + lane * 8;
                pf[i] = *(const f16x8*)g;
            }
        }

        f16x8 a[4], b[4];
        #pragma unroll
        for (int i = 0; i < 4; ++i) {
            a[i] = *(const f16x8*)&cur[(quad * 128 + wm + i * 16 + lq) * 8];
            b[i] = *(const f16x8*)&cur[4096 + (quad * 128 + wn + i * 16 + lq) * 8];
        }
        #pragma unroll
        for (int i = 0; i < 4; ++i)
            #pragma unroll
            for (int j = 0; j < 4; ++j)
                acc[i][j] = __builtin_amdgcn_mfma_f32_16x16x32_f16(a[i], b[j], acc[i][j], 0, 0, 0);

        if (kt + 1 < 32) {
            #pragma unroll
            for (int i = 0; i < 4; ++i)
                *(f16x8*)&sm[((kt + 1) & 1) * 8192 + (c0 + i) * 512 + lane * 8] = pf[i];
        }
        __syncthreads();
    }

    const int bb = mb >> 4;
    #pragma unroll
    for (int jf = 0; jf < 4; ++jf) {
        const int col = nb * 128 + wn + jf * 16 + lq;
        const int h = col / 192;
        const int sect = col - h * 192;
        const int type = sect >> 6;
        const int c = sect & 63;
        const float bv = bias[col];
        const size_t bh = (size_t)bb * 16 + h;
        #pragma unroll
        for (int i = 0; i < 4; ++i) {
            #pragma unroll
            for (int r = 0; r < 4; ++r) {
                const int n = (mb & 15) * 128 + wm + i * 16 + quad * 4 + r;
                const float v = acc[i][jf][r] + bv;
                if (type == 0) {
                    const size_t a2 = ((bh * 16 + (n >> 7)) * 8 + (c >> 3)) * 1024
                                      + (size_t)(n & 127) * 8 + (c & 7);
                    qg[a2] = __float2half(v * QSCALE);
                } else if (type == 1) {
                    const size_t a2 = ((bh * 32 + (n >> 6)) * 8 + (c >> 3)) * 512
                                      + (size_t)(n & 63) * 8 + (c & 7);
                    kg[a2] = __float2half(v);
                } else {
                    const size_t a2 = ((bh * 32 + (n >> 6)) * 8 + ((n >> 3) & 7)) * 512
                                      + (size_t)c * 8 + (n & 7);
                    vtg[a2] = __float2half(v);
                }
            }
        }
    }
}

// ===========================================================================
// Attention v12 = v10 with PHASE-SPLIT main loop: all S^T MFMAs (8 indep
// K=32), then all softmax VALU (16 exp2 + 8 pkrtz + 12 adds), then all 16
// PV MFMAs.  R9 counters showed MfmaUtil 44 + VALUBusy 48 ~= 92% of dur:
// pipes alternating, not overlapping.  Homogeneous phases let wave A's MFMA
// phase overlap wave B's VALU phase on the same SIMD (2 waves/SIMD).
// Zero-LDS main loop, key-partitioned waves, static register indices.
// ===========================================================================
__global__ __launch_bounds__(256, 2)
void attn_mfma12(const __half* __restrict__ qg, const __half* __restrict__ kg,
                 const __half* __restrict__ vtg, __half* __restrict__ a2)
{
    __shared__ __align__(16) float red[4][3][2][16][16];  // 24 KB: [qn][src][jj][ch][q]
    __shared__ __align__(16) float rol2[4][4][16];        // 1 KB: [qn][wave][lq] l partials

    const int t = threadIdx.x, lane = t & 63, w = t >> 6;
    const int lq = lane & 15, quad = lane >> 4;
    const int bid = blockIdx.x;
    // XCD swizzle: bid&7 selects bh mod 8 -> all 32 q-tiles of a bh on one XCD.
    const int qt = (bid >> 3) & 31;                  // 64-row q tile [0,32)
    const int bh_ = (bid & 7) + ((bid >> 8) << 3);
    const size_t bh = (size_t)bh_;
    const int h = bh_ & 15, b = bh_ >> 4;

    const __half* qtile = qg + (bh * 16 + (qt >> 1)) * 8192;
    const __half* kbase = kg + bh * 32 * 4096;
    const __half* vbase = vtg + bh * 32 * 4096;

    // ---- Q fragments, direct global->reg: aq[qn][ks] = Q^T[ch][q] ----
    const int qrow0 = (qt & 1) * 64;
    f16x8 aq[4][2];
    #pragma unroll
    for (int qn = 0; qn < 4; ++qn)
        #pragma unroll
        for (int ks = 0; ks < 2; ++ks)
            aq[qn][ks] = *(const f16x8*)(qtile + (size_t)(ks * 4 + quad) * 1024
                                         + (qrow0 + qn * 16 + lq) * 8);

    // ---- per-lane K/V offsets within a kt tile (in halves) ----
    const int kofs0 = ((0 * 4 + quad) * 64 + w * 16 + lq) * 8;
    const int kofs1 = ((1 * 4 + quad) * 64 + w * 16 + lq) * 8;
    int vofs[4];
    #pragma unroll
    for (int jc = 0; jc < 4; ++jc)
        vofs[jc] = ((w * 2 + (quad >> 1)) * 64 + jc * 16 + lq) * 8 + (quad & 1) * 4;

    f32x4 O[4][4];
    float ls[4];
    #pragma unroll
    for (int qn = 0; qn < 4; ++qn) {
        ls[qn] = 0.0f;
        #pragma unroll
        for (int jc = 0; jc < 4; ++jc) O[qn][jc] = 0;
    }
    const f32x4 zc = {0.0f, 0.0f, 0.0f, 0.0f};

    // ---- prologue: load tile 0 ----
    f16x8 kf0 = *(const f16x8*)(kbase + kofs0);
    f16x8 kf1 = *(const f16x8*)(kbase + kofs1);
    f16x4 vf[4];
    #pragma unroll
    for (int jc = 0; jc < 4; ++jc) vf[jc] = *(const f16x4*)(vbase + vofs[jc]);

    const __half* kp = kbase + 4096;
    const __half* vp = vbase + 4096;

    for (int kt = 0; kt < 32; ++kt) {
        // prefetch tile kt+1 (wave-private, no sharing, no LDS)
        f16x8 kn0, kn1; f16x4 vn[4];
        if (kt < 31) {
            kn0 = *(const f16x8*)(kp + kofs0);
            kn1 = *(const f16x8*)(kp + kofs1);
            #pragma unroll
            for (int jc = 0; jc < 4; ++jc) vn[jc] = *(const f16x4*)(vp + vofs[jc]);
            kp += 4096; vp += 4096;
        }

        // ---- phase 1: all S^T MFMAs (8 x K=32, 4 independent chains) ----
        f32x4 st[4];
        __builtin_amdgcn_s_setprio(1);
        #pragma unroll
        for (int qn = 0; qn < 4; ++qn)
            st[qn] = __builtin_amdgcn_mfma_f32_16x16x32_f16(kf0, aq[qn][0], zc, 0, 0, 0);
        #pragma unroll
        for (int qn = 0; qn < 4; ++qn)
            st[qn] = __builtin_amdgcn_mfma_f32_16x16x32_f16(kf1, aq[qn][1], st[qn], 0, 0, 0);
        __builtin_amdgcn_s_setprio(0);

        // ---- phase 2: all softmax VALU (exp2 + l + pack) ----
        f16x4 pa[4];
        #pragma unroll
        for (int qn = 0; qn < 4; ++qn) {
            const float e0 = __builtin_amdgcn_exp2f(st[qn][0]);
            const float e1 = __builtin_amdgcn_exp2f(st[qn][1]);
            const float e2 = __builtin_amdgcn_exp2f(st[qn][2]);
            const float e3 = __builtin_amdgcn_exp2f(st[qn][3]);
            ls[qn] += (e0 + e1) + (e2 + e3);
            uint2 pk;
            pk.x = pkrtz(e0, e1);
            pk.y = pkrtz(e2, e3);
            pa[qn] = __builtin_bit_cast(f16x4, pk);
        }

        // ---- phase 3: all PV MFMAs (16 x K=16, 16 independent chains) ----
        __builtin_amdgcn_s_setprio(1);
        #pragma unroll
        for (int qn = 0; qn < 4; ++qn)
            #pragma unroll
            for (int jc = 0; jc < 4; ++jc)
                O[qn][jc] = __builtin_amdgcn_mfma_f32_16x16x16f16(pa[qn], vf[jc], O[qn][jc], 0, 0, 0);
        __builtin_amdgcn_s_setprio(0);

        if (kt < 31) {
            kf0 = kn0; kf1 = kn1;
            #pragma unroll
            for (int jc = 0; jc < 4; ++jc) vf[jc] = vn[jc];
        }
    }

    // ---- wave-reduce l over the 4 quad-lanes (same lq) ----
    float lsw[4];
    #pragma unroll
    for (int qn = 0; qn < 4; ++qn) {
        float v = ls[qn];
        v += __shfl_xor(v, 16, 64);
        v += __shfl_xor(v, 32, 64);
        lsw[qn] = v;
    }

    // ---- epilogue: reduce O, l across the 4 key-slice waves via LDS ----
    #pragma unroll
    for (int qn = 0; qn < 4; ++qn) {
        if (quad == 0)
            rol2[qn][w][lq] = lsw[qn];           // 16 lanes write l[lq]
        if (qn != w) {
            const int rel = (w < qn) ? w : w - 1;
            *(f32x4*)&red[qn][rel][0][lq][quad * 4] = O[qn][0];
            *(f32x4*)&red[qn][rel][1][lq][quad * 4] = O[qn][1];
        }
    }
    __syncthreads();

    float linv[4];
    f32x4 s0 = zc, s1 = zc;
    #pragma unroll
    for (int qn = 0; qn < 4; ++qn) {
        if (qn == w) {
            f32x4 lt = zc;
            #pragma unroll
            for (int w2 = 0; w2 < 4; ++w2)
                lt += *(const f32x4*)&rol2[qn][w2][quad * 4];
            #pragma unroll
            for (int r = 0; r < 4; ++r) linv[r] = 1.0f / lt[r];
            s0 = O[qn][0];
            s1 = O[qn][1];
            #pragma unroll
            for (int src = 0; src < 3; ++src) {
                s0 += *(const f32x4*)&red[qn][src][0][lq][quad * 4];
                s1 += *(const f32x4*)&red[qn][src][1][lq][quad * 4];
            }
        }
    }

    __half* a2t = a2 + ((size_t)(b * 16 + (qt >> 1)) * 32) * 4096;
    const int mb0 = (qt & 1) * 64 + w * 16 + quad * 4;

    // store jc 0,1
    {
        const int ch0 = h * 64 + 0 * 16 + lq;
        const int ktp0 = ch0 >> 5, qc0 = (ch0 >> 3) & 3, j0 = ch0 & 7;
        #pragma unroll
        for (int r = 0; r < 4; ++r)
            a2t[(size_t)ktp0 * 4096 + (qc0 * 128 + mb0 + r) * 8 + j0] =
                __float2half(s0[r] * linv[r]);
        const int ch1 = h * 64 + 1 * 16 + lq;
        const int ktp1 = ch1 >> 5, qc1 = (ch1 >> 3) & 3, j1 = ch1 & 7;
        #pragma unroll
        for (int r = 0; r < 4; ++r)
            a2t[(size_t)ktp1 * 4096 + (qc1 * 128 + mb0 + r) * 8 + j1] =
                __float2half(s1[r] * linv[r]);
    }
    __syncthreads();

    // round 1: jc 2,3
    #pragma unroll
    for (int qn = 0; qn < 4; ++qn) {
        if (qn != w) {
            const int rel = (w < qn) ? w : w - 1;
            *(f32x4*)&red[qn][rel][0][lq][quad * 4] = O[qn][2];
            *(f32x4*)&red[qn][rel][1][lq][quad * 4] = O[qn][3];
        }
    }
    __syncthreads();

    f32x4 s2 = zc, s3 = zc;
    #pragma unroll
    for (int qn = 0; qn < 4; ++qn) {
        if (qn == w) {
            s2 = O[qn][2];
            s3 = O[qn][3];
            #pragma unroll
            for (int src = 0; src < 3; ++src) {
                s2 += *(const f32x4*)&red[qn][src][0][lq][quad * 4];
                s3 += *(const f32x4*)&red[qn][src][1][lq][quad * 4];
            }
        }
    }

    {
        const int ch2 = h * 64 + 2 * 16 + lq;
        const int ktp2 = ch2 >> 5, qc2 = (ch2 >> 3) & 3, j2 = ch2 & 7;
        #pragma unroll
        for (int r = 0; r < 4; ++r)
            a2t[(size_t)ktp2 * 4096 + (qc2 * 128 + mb0 + r) * 8 + j2] =
                __float2half(s2[r] * linv[r]);
        const int ch3 = h * 64 + 3 * 16 + lq;
        const int ktp3 = ch3 >> 5, qc3 = (ch3 >> 3) & 3, j3 = ch3 & 7;
        #pragma unroll
        for (int r = 0; r < 4; ++r)
            a2t[(size_t)ktp3 * 4096 + (qc3 * 128 + mb0 + r) * 8 + j3] =
                __float2half(s3[r] * linv[r]);
    }
}

// ===========================================================================
// Proj GEMM (R7 winner config): 256 threads / 4 waves, 128x128 tile,
// register-prefetch + LDS double-buffer.  (512-thread 8-wave variant
// regressed in R9 — halved per-wave work, more barrier cost.)
// ===========================================================================
__global__ __launch_bounds__(256)
void gemm_proj(const __half* __restrict__ At, const __half* __restrict__ Bt,
               const float* __restrict__ bias, float* __restrict__ out)
{
    __shared__ __align__(16) _Float16 sm[16384];
    const int t = threadIdx.x, lane = t & 63, w = t >> 6;
    const int lq = lane & 15, quad = lane >> 4;
    const int nb = blockIdx.x, mb = blockIdx.y;
    const int wm = (w >> 1) * 64, wn = (w & 1) * 64;

    const __half* Ab = At + ((size_t)mb * 32) * 4096;
    const __half* Bb = Bt + ((size_t)nb * 32) * 4096;
    const int c0 = w * 4;

    f32x4 acc[4][4];
    #pragma unroll
    for (int i = 0; i < 4; ++i)
        #pragma unroll
        for (int j = 0; j < 4; ++j) acc[i][j] = 0;

    f16x8 pf[4];
    #pragma unroll
    for (int i = 0; i < 4; ++i) {
        const int c = c0 + i;
        const __half* g = (c < 8 ? Ab + c * 512 : Bb + (c - 8) * 512) + lane * 8;
        pf[i] = *(const f16x8*)g;
    }
    #pragma unroll
    for (int i = 0; i < 4; ++i)
        *(f16x8*)&sm[(c0 + i) * 512 + lane * 8] = pf[i];
    __syncthreads();

    for (int kt = 0; kt < 32; ++kt) {
        _Float16* cur = sm + (kt & 1) * 8192;

        if (kt + 1 < 32) {
            #pragma unroll
            for (int i = 0; i < 4; ++i) {
                const int c = c0 + i;
                const __half* g = (c < 8 ? Ab + (size_t)(kt + 1) * 4096 + c * 512
                                         : Bb + (size_t)(kt + 1) * 4096 + (c - 8) * 512) + lane * 8;
                pf[i] = *(const f16x8*)g;
            }
        }

        f16x8 a[4], b[4];
        #pragma unroll
        for (int i = 0; i < 4; ++i) {
            a[i] = *(const f16x8*)&cur[(quad * 128 + wm + i * 16 + lq) * 8];
            b[i] = *(const f16x8*)&cur[4096 + (quad * 128 + wn + i * 16 + lq) * 8];
        }
        #pragma unroll
        for (int i = 0; i < 4; ++i)
            #pragma unroll
            for (int j = 0; j < 4; ++j)
                acc[i][j] = __builtin_amdgcn_mfma_f32_16x16x32_f16(a[i], b[j], acc[i][j], 0, 0, 0);

        if (kt + 1 < 32) {
            #pragma unroll
            for (int i = 0; i < 4; ++i)
                *(f16x8*)&sm[((kt + 1) & 1) * 8192 + (c0 + i) * 512 + lane * 8] = pf[i];
        }
        __syncthreads();
    }

    #pragma unroll
    for (int jf = 0; jf < 4; ++jf) {
        const int col = nb * 128 + wn + jf * 16 + lq;
        const float bv = bias[col];
        #pragma unroll
        for (int i = 0; i < 4; ++i)
            #pragma unroll
            for (int r = 0; r < 4; ++r) {
                const int row = mb * 128 + wm + i * 16 + quad * 4 + r;
                out[(size_t)row * WIDTH + col] = acc[i][jf][r] + bv;
            }
    }
}

// ===========================================================================
extern "C" void kernel_launch(void* const* d_in, const int* in_sizes, int n_in,
                              void* d_out, int out_size, void* d_ws, size_t ws_size,
                              hipStream_t stream)
{
    const float* x      = (const float*)d_in[0];
    const float* w_qkv  = (const float*)d_in[1];
    const float* b_qkv  = (const float*)d_in[2];
    const float* w_proj = (const float*)d_in[3];
    const float* b_proj = (const float*)d_in[4];
    float* out = (float*)d_out;

    char* p = (char*)d_ws;
    size_t o = 0;
    __half* A1  = (__half*)(p + o); o += (size_t)MROWS * WIDTH * 2;
    __half* Bq  = (__half*)(p + o); o += (size_t)WIDTH * QKVD * 2;
    __half* Qg  = (__half*)(p + o); o += (size_t)MROWS * WIDTH * 2;
    __half* Kg  = (__half*)(p + o); o += (size_t)MROWS * WIDTH * 2;
    __half* Vtg = (__half*)(p + o); o += (size_t)MROWS * WIDTH * 2;
    __half* A2  = (__half*)(p + o); o += (size_t)MROWS * WIDTH * 2;
    __half* Bp  = (__half*)(p + o); o += (size_t)WIDTH * WIDTH * 2;

    split_all<<<dim3(2048), dim3(256), 0, stream>>>(x, w_qkv, w_proj, A1, Bq, Bp);

    gemm_qkv<<<dim3(24, 32), dim3(256), 0, stream>>>(A1, Bq, b_qkv, Qg, Kg, Vtg);

    attn_mfma12<<<dim3(1024), dim3(256), 0, stream>>>(Qg, Kg, Vtg, A2);

    gemm_proj<<<dim3(8, 32), dim3(256), 0, stream>>>(A2, Bp, b_proj, out);
}

// Round 11
// 187.273 us; speedup vs baseline: 1.0868x; 1.0216x over previous
//
#include <hip/hip_runtime.h>
#include <hip/hip_fp16.h>

#define BATCH 2
#define NCTX  2048
#define WIDTH 1024
#define HEADS 16
#define CH    64
#define QKVD  (3 * WIDTH)
#define MROWS (BATCH * NCTX)

typedef __attribute__((ext_vector_type(4))) float    f32x4;
typedef __attribute__((ext_vector_type(8))) _Float16 f16x8;
typedef __attribute__((ext_vector_type(4))) _Float16 f16x4;

// 0.125 (= softmax scale^2) * log2(e), folded into Q so P = exp2(S')
#define QSCALE 0.18033688011112042f

// pack two f32 -> two f16 (RTZ) as one 32-bit word
__device__ __forceinline__ unsigned pkrtz(float a, float b) {
    auto p = __builtin_amdgcn_cvt_pkrtz(a, b);
    return __builtin_bit_cast(unsigned, p);
}

// ===========================================================================
// Fused split: one launch covers
//   bid [0,1024):    x [4096][1024] f32 -> A1 tiles [mb 32][kt 32][4096]
//   bid [1024,1792): w_qkv -> Bq tiles (transpose), N=3072
//   bid [1792,2048): w_proj -> Bp tiles (transpose), N=1024
// ===========================================================================
__global__ __launch_bounds__(256)
void split_all(const float* __restrict__ x,
               const float* __restrict__ w_qkv, const float* __restrict__ w_proj,
               __half* __restrict__ A1, __half* __restrict__ Bq, __half* __restrict__ Bp)
{
    __shared__ float tile[32][129];
    const int bid = blockIdx.x;
    const int t = threadIdx.x;

    if (bid < 1024) {
        const int mb = bid >> 5, kt = bid & 31;
        __half* tb = A1 + ((size_t)mb * 32 + kt) * 4096;
        #pragma unroll
        for (int it = 0; it < 2; ++it) {
            const int idx = it * 256 + t;       // 512 cells (m, q)
            const int m = idx >> 2, q = idx & 3;
            const float* src = x + (size_t)(mb * 128 + m) * WIDTH + kt * 32 + q * 8;
            const f32x4 v0 = *(const f32x4*)src;
            const f32x4 v1 = *(const f32x4*)(src + 4);
            f16x8 h;
            #pragma unroll
            for (int j = 0; j < 4; ++j) { h[j] = (_Float16)v0[j]; h[4 + j] = (_Float16)v1[j]; }
            *(f16x8*)&tb[(q * 128 + m) * 8] = h;
        }
        return;
    }

    const float* w; __half* tiles; int N, nb, kt;
    if (bid < 1792) {
        const int u = bid - 1024;
        w = w_qkv; tiles = Bq; N = QKVD; nb = u >> 5; kt = u & 31;
    } else {
        const int u = bid - 1792;
        w = w_proj; tiles = Bp; N = WIDTH; nb = u >> 5; kt = u & 31;
    }

    #pragma unroll
    for (int it = 0; it < 2; ++it) {
        const int idx = it * 256 + t;       // 512 x 8 floats
        const int kk = idx >> 4, n8 = idx & 15;
        const float* src = w + (size_t)(kt * 32 + kk) * N + nb * 128 + n8 * 8;
        #pragma unroll
        for (int j = 0; j < 8; ++j) tile[kk][n8 * 8 + j] = src[j];
    }
    __syncthreads();
    __half* tb = tiles + ((size_t)nb * 32 + kt) * 4096;
    #pragma unroll
    for (int it = 0; it < 2; ++it) {
        const int idx = it * 256 + t;       // 512 cells (q, nn)
        const int q = idx >> 7, nn = idx & 127;
        f16x8 h;
        #pragma unroll
        for (int j = 0; j < 8; ++j) h[j] = (_Float16)tile[q * 8 + j][nn];
        *(f16x8*)&tb[(q * 128 + nn) * 8] = h;
    }
}

// ===========================================================================
// QKV GEMM: 128x128x32 fp16 MFMA, register-prefetch + LDS double-buffer,
// one barrier per K-iter. Epilogue scatters Q (scaled by QSCALE), K, V^T.
// ===========================================================================
__global__ __launch_bounds__(256)
void gemm_qkv(const __half* __restrict__ At, const __half* __restrict__ Bt,
              const float* __restrict__ bias,
              __half* __restrict__ qg, __half* __restrict__ kg, __half* __restrict__ vtg)
{
    __shared__ __align__(16) _Float16 sm[16384];    // 2 buffers x (A 4096 | B 4096)
    const int t = threadIdx.x, lane = t & 63, w = t >> 6;
    const int lq = lane & 15, quad = lane >> 4;
    const int nb = blockIdx.x, mb = blockIdx.y;
    const int wm = (w >> 1) * 64, wn = (w & 1) * 64;

    const __half* Ab = At + ((size_t)mb * 32) * 4096;
    const __half* Bb = Bt + ((size_t)nb * 32) * 4096;
    const int c0 = w * 4;

    f32x4 acc[4][4];
    #pragma unroll
    for (int i = 0; i < 4; ++i)
        #pragma unroll
        for (int j = 0; j < 4; ++j) acc[i][j] = 0;

    f16x8 pf[4];
    #pragma unroll
    for (int i = 0; i < 4; ++i) {
        const int c = c0 + i;
        const __half* g = (c < 8 ? Ab + c * 512 : Bb + (c - 8) * 512) + lane * 8;
        pf[i] = *(const f16x8*)g;
    }
    #pragma unroll
    for (int i = 0; i < 4; ++i)
        *(f16x8*)&sm[(c0 + i) * 512 + lane * 8] = pf[i];
    __syncthreads();

    for (int kt = 0; kt < 32; ++kt) {
        _Float16* cur = sm + (kt & 1) * 8192;

        if (kt + 1 < 32) {
            #pragma unroll
            for (int i = 0; i < 4; ++i) {
                const int c = c0 + i;
                const __half* g = (c < 8 ? Ab + (size_t)(kt + 1) * 4096 + c * 512
                                         : Bb + (size_t)(kt + 1) * 4096 + (c - 8) * 512) + lane * 8;
                pf[i] = *(const f16x8*)g;
            }
        }

        f16x8 a[4], b[4];
        #pragma unroll
        for (int i = 0; i < 4; ++i) {
            a[i] = *(const f16x8*)&cur[(quad * 128 + wm + i * 16 + lq) * 8];
            b[i] = *(const f16x8*)&cur[4096 + (quad * 128 + wn + i * 16 + lq) * 8];
        }
        #pragma unroll
        for (int i = 0; i < 4; ++i)
            #pragma unroll
            for (int j = 0; j < 4; ++j)
                acc[i][j] = __builtin_amdgcn_mfma_f32_16x16x32_f16(a[i], b[j], acc[i][j], 0, 0, 0);

        if (kt + 1 < 32) {
            #pragma unroll
            for (int i = 0; i < 4; ++i)
                *(f16x8*)&sm[((kt + 1) & 1) * 8192 + (c0 + i) * 512 + lane * 8] = pf[i];
        }
        __syncthreads();
    }

    const int bb = mb >> 4;
    #pragma unroll
    for (int jf = 0; jf < 4; ++jf) {
        const int col = nb * 128 + wn + jf * 16 + lq;
        const int h = col / 192;
        const int sect = col - h * 192;
        const int type = sect >> 6;
        const int c = sect & 63;
        const float bv = bias[col];
        const size_t bh = (size_t)bb * 16 + h;
        #pragma unroll
        for (int i = 0; i < 4; ++i) {
            #pragma unroll
            for (int r = 0; r < 4; ++r) {
                const int n = (mb & 15) * 128 + wm + i * 16 + quad * 4 + r;
                const float v = acc[i][jf][r] + bv;
                if (type == 0) {
                    const size_t a2 = ((bh * 16 + (n >> 7)) * 8 + (c >> 3)) * 1024
                                      + (size_t)(n & 127) * 8 + (c & 7);
                    qg[a2] = __float2half(v * QSCALE);
                } else if (type == 1) {
                    const size_t a2 = ((bh * 32 + (n >> 6)) * 8 + (c >> 3)) * 512
                                      + (size_t)(n & 63) * 8 + (c & 7);
                    kg[a2] = __float2half(v);
                } else {
                    const size_t a2 = ((bh * 32 + (n >> 6)) * 8 + ((n >> 3) & 7)) * 512
                                      + (size_t)c * 8 + (n & 7);
                    vtg[a2] = __float2half(v);
                }
            }
        }
    }
}

// ===========================================================================
// Attention v13 = v10 (R7/R9 winner: interleaved per-qn chain, zero-LDS main
// loop, l on VALU + shfl reduce, setprio) with __launch_bounds__(256, 3):
// actual demand ~84 VGPR + 64 AGPR = 148 <= 168 cap -> 3 waves/SIMD
// (was pinned at 2 by the 256-reg allocation the (256,2) bound permitted).
// Spill tripwire: WRITE_SIZE must stay ~8.2 MB.
// ===========================================================================
__global__ __launch_bounds__(256, 3)
void attn_mfma13(const __half* __restrict__ qg, const __half* __restrict__ kg,
                 const __half* __restrict__ vtg, __half* __restrict__ a2)
{
    __shared__ __align__(16) float red[4][3][2][16][16];  // 24 KB: [qn][src][jj][ch][q]
    __shared__ __align__(16) float rol2[4][4][16];        // 1 KB: [qn][wave][lq] l partials

    const int t = threadIdx.x, lane = t & 63, w = t >> 6;
    const int lq = lane & 15, quad = lane >> 4;
    const int bid = blockIdx.x;
    // XCD swizzle: bid&7 selects bh mod 8 -> all 32 q-tiles of a bh on one XCD.
    const int qt = (bid >> 3) & 31;                  // 64-row q tile [0,32)
    const int bh_ = (bid & 7) + ((bid >> 8) << 3);
    const size_t bh = (size_t)bh_;
    const int h = bh_ & 15, b = bh_ >> 4;

    const __half* qtile = qg + (bh * 16 + (qt >> 1)) * 8192;
    const __half* kbase = kg + bh * 32 * 4096;
    const __half* vbase = vtg + bh * 32 * 4096;

    // ---- Q fragments, direct global->reg: aq[qn][ks] = Q^T[ch][q] ----
    const int qrow0 = (qt & 1) * 64;
    f16x8 aq[4][2];
    #pragma unroll
    for (int qn = 0; qn < 4; ++qn)
        #pragma unroll
        for (int ks = 0; ks < 2; ++ks)
            aq[qn][ks] = *(const f16x8*)(qtile + (size_t)(ks * 4 + quad) * 1024
                                         + (qrow0 + qn * 16 + lq) * 8);

    // ---- per-lane K/V offsets within a kt tile (in halves) ----
    const int kofs0 = ((0 * 4 + quad) * 64 + w * 16 + lq) * 8;
    const int kofs1 = ((1 * 4 + quad) * 64 + w * 16 + lq) * 8;
    int vofs[4];
    #pragma unroll
    for (int jc = 0; jc < 4; ++jc)
        vofs[jc] = ((w * 2 + (quad >> 1)) * 64 + jc * 16 + lq) * 8 + (quad & 1) * 4;

    f32x4 O[4][4];
    float ls[4];
    #pragma unroll
    for (int qn = 0; qn < 4; ++qn) {
        ls[qn] = 0.0f;
        #pragma unroll
        for (int jc = 0; jc < 4; ++jc) O[qn][jc] = 0;
    }
    const f32x4 zc = {0.0f, 0.0f, 0.0f, 0.0f};

    // ---- prologue: load tile 0 ----
    f16x8 kf0 = *(const f16x8*)(kbase + kofs0);
    f16x8 kf1 = *(const f16x8*)(kbase + kofs1);
    f16x4 vf[4];
    #pragma unroll
    for (int jc = 0; jc < 4; ++jc) vf[jc] = *(const f16x4*)(vbase + vofs[jc]);

    const __half* kp = kbase + 4096;
    const __half* vp = vbase + 4096;

    for (int kt = 0; kt < 32; ++kt) {
        // prefetch tile kt+1 (wave-private, no sharing, no LDS)
        f16x8 kn0, kn1; f16x4 vn[4];
        if (kt < 31) {
            kn0 = *(const f16x8*)(kp + kofs0);
            kn1 = *(const f16x8*)(kp + kofs1);
            #pragma unroll
            for (int jc = 0; jc < 4; ++jc) vn[jc] = *(const f16x4*)(vp + vofs[jc]);
            kp += 4096; vp += 4096;
        }

        __builtin_amdgcn_s_setprio(1);
        #pragma unroll
        for (int qn = 0; qn < 4; ++qn) {
            // S^T: D[key16][q16] over ch=64 (2 x K=32 MFMA)
            f32x4 st = __builtin_amdgcn_mfma_f32_16x16x32_f16(kf0, aq[qn][0], zc, 0, 0, 0);
            st = __builtin_amdgcn_mfma_f32_16x16x32_f16(kf1, aq[qn][1], st, 0, 0, 0);
            // P = exp2(S'), pack to f16x4 == PV A-fragment (k=quad*4+r, row=lq)
            const float e0 = __builtin_amdgcn_exp2f(st[0]);
            const float e1 = __builtin_amdgcn_exp2f(st[1]);
            const float e2 = __builtin_amdgcn_exp2f(st[2]);
            const float e3 = __builtin_amdgcn_exp2f(st[3]);
            ls[qn] += (e0 + e1) + (e2 + e3);     // l partial on VALU pipe
            uint2 pk;
            pk.x = pkrtz(e0, e1);
            pk.y = pkrtz(e2, e3);
            const f16x4 pa = __builtin_bit_cast(f16x4, pk);
            // O += P^T x V   (all register-resident)
            #pragma unroll
            for (int jc = 0; jc < 4; ++jc)
                O[qn][jc] = __builtin_amdgcn_mfma_f32_16x16x16f16(pa, vf[jc], O[qn][jc], 0, 0, 0);
        }
        __builtin_amdgcn_s_setprio(0);

        if (kt < 31) {
            kf0 = kn0; kf1 = kn1;
            #pragma unroll
            for (int jc = 0; jc < 4; ++jc) vf[jc] = vn[jc];
        }
    }

    // ---- wave-reduce l over the 4 quad-lanes (same lq) ----
    float lsw[4];
    #pragma unroll
    for (int qn = 0; qn < 4; ++qn) {
        float v = ls[qn];
        v += __shfl_xor(v, 16, 64);
        v += __shfl_xor(v, 32, 64);
        lsw[qn] = v;
    }

    // ---- epilogue: reduce O, l across the 4 key-slice waves via LDS ----
    #pragma unroll
    for (int qn = 0; qn < 4; ++qn) {
        if (quad == 0)
            rol2[qn][w][lq] = lsw[qn];           // 16 lanes write l[lq]
        if (qn != w) {
            const int rel = (w < qn) ? w : w - 1;
            *(f32x4*)&red[qn][rel][0][lq][quad * 4] = O[qn][0];
            *(f32x4*)&red[qn][rel][1][lq][quad * 4] = O[qn][1];
        }
    }
    __syncthreads();

    float linv[4];
    f32x4 s0 = zc, s1 = zc;
    #pragma unroll
    for (int qn = 0; qn < 4; ++qn) {
        if (qn == w) {
            f32x4 lt = zc;
            #pragma unroll
            for (int w2 = 0; w2 < 4; ++w2)
                lt += *(const f32x4*)&rol2[qn][w2][quad * 4];
            #pragma unroll
            for (int r = 0; r < 4; ++r) linv[r] = 1.0f / lt[r];
            s0 = O[qn][0];
            s1 = O[qn][1];
            #pragma unroll
            for (int src = 0; src < 3; ++src) {
                s0 += *(const f32x4*)&red[qn][src][0][lq][quad * 4];
                s1 += *(const f32x4*)&red[qn][src][1][lq][quad * 4];
            }
        }
    }

    __half* a2t = a2 + ((size_t)(b * 16 + (qt >> 1)) * 32) * 4096;
    const int mb0 = (qt & 1) * 64 + w * 16 + quad * 4;

    // store jc 0,1
    {
        const int ch0 = h * 64 + 0 * 16 + lq;
        const int ktp0 = ch0 >> 5, qc0 = (ch0 >> 3) & 3, j0 = ch0 & 7;
        #pragma unroll
        for (int r = 0; r < 4; ++r)
            a2t[(size_t)ktp0 * 4096 + (qc0 * 128 + mb0 + r) * 8 + j0] =
                __float2half(s0[r] * linv[r]);
        const int ch1 = h * 64 + 1 * 16 + lq;
        const int ktp1 = ch1 >> 5, qc1 = (ch1 >> 3) & 3, j1 = ch1 & 7;
        #pragma unroll
        for (int r = 0; r < 4; ++r)
            a2t[(size_t)ktp1 * 4096 + (qc1 * 128 + mb0 + r) * 8 + j1] =
                __float2half(s1[r] * linv[r]);
    }
    __syncthreads();

    // round 1: jc 2,3
    #pragma unroll
    for (int qn = 0; qn < 4; ++qn) {
        if (qn != w) {
            const int rel = (w < qn) ? w : w - 1;
            *(f32x4*)&red[qn][rel][0][lq][quad * 4] = O[qn][2];
            *(f32x4*)&red[qn][rel][1][lq][quad * 4] = O[qn][3];
        }
    }
    __syncthreads();

    f32x4 s2 = zc, s3 = zc;
    #pragma unroll
    for (int qn = 0; qn < 4; ++qn) {
        if (qn == w) {
            s2 = O[qn][2];
            s3 = O[qn][3];
            #pragma unroll
            for (int src = 0; src < 3; ++src) {
                s2 += *(const f32x4*)&red[qn][src][0][lq][quad * 4];
                s3 += *(const f32x4*)&red[qn][src][1][lq][quad * 4];
            }
        }
    }

    {
        const int ch2 = h * 64 + 2 * 16 + lq;
        const int ktp2 = ch2 >> 5, qc2 = (ch2 >> 3) & 3, j2 = ch2 & 7;
        #pragma unroll
        for (int r = 0; r < 4; ++r)
            a2t[(size_t)ktp2 * 4096 + (qc2 * 128 + mb0 + r) * 8 + j2] =
                __float2half(s2[r] * linv[r]);
        const int ch3 = h * 64 + 3 * 16 + lq;
        const int ktp3 = ch3 >> 5, qc3 = (ch3 >> 3) & 3, j3 = ch3 & 7;
        #pragma unroll
        for (int r = 0; r < 4; ++r)
            a2t[(size_t)ktp3 * 4096 + (qc3 * 128 + mb0 + r) * 8 + j3] =
                __float2half(s3[r] * linv[r]);
    }
}

// ===========================================================================
// Proj GEMM v2: 128x64 tiles -> grid 512 = 2 blocks/CU (was 256 = 1/CU).
// Two INDEPENDENT blocks per CU overlap across their separate barriers
// (unlike R9's 8-wave single-block variant).  4 waves, wave = 64x32 subtile,
// acc 4x2; staging 3 chunks/wave (A 8 + B 4 = 12 chunks of 512 halves).
// B read from the 128-wide Bp tile format via (nb&1)*512 offset.
// ===========================================================================
__global__ __launch_bounds__(256)
void gemm_proj(const __half* __restrict__ At, const __half* __restrict__ Bt,
               const float* __restrict__ bias, float* __restrict__ out)
{
    __shared__ __align__(16) _Float16 sm[12288];    // 2 x (A 4096 | B 2048)
    const int t = threadIdx.x, lane = t & 63, w = t >> 6;
    const int lq = lane & 15, quad = lane >> 4;
    const int nb = blockIdx.x, mb = blockIdx.y;     // nb in [0,16), mb in [0,32)
    const int wm = (w >> 1) * 64, wn = (w & 1) * 32;

    const __half* Ab = At + ((size_t)mb * 32) * 4096;
    const __half* Bb = Bt + ((size_t)(nb >> 1) * 32) * 4096 + (nb & 1) * 512;
    const int c0 = w * 3;

    f32x4 acc[4][2];
    #pragma unroll
    for (int i = 0; i < 4; ++i)
        #pragma unroll
        for (int j = 0; j < 2; ++j) acc[i][j] = 0;

    f16x8 pf[3];
    #pragma unroll
    for (int i = 0; i < 3; ++i) {
        const int c = c0 + i;
        const __half* g = (c < 8 ? Ab + c * 512 : Bb + (c - 8) * 1024) + lane * 8;
        pf[i] = *(const f16x8*)g;
    }
    #pragma unroll
    for (int i = 0; i < 3; ++i) {
        const int c = c0 + i;
        _Float16* d = (c < 8) ? &sm[c * 512] : &sm[4096 + (c - 8) * 512];
        *(f16x8*)&d[lane * 8] = pf[i];
    }
    __syncthreads();

    for (int kt = 0; kt < 32; ++kt) {
        _Float16* cur = sm + (kt & 1) * 6144;

        if (kt + 1 < 32) {
            #pragma unroll
            for (int i = 0; i < 3; ++i) {
                const int c = c0 + i;
                const __half* g = (c < 8 ? Ab + (size_t)(kt + 1) * 4096 + c * 512
                                         : Bb + (size_t)(kt + 1) * 4096 + (c - 8) * 1024) + lane * 8;
                pf[i] = *(const f16x8*)g;
            }
        }

        f16x8 a[4], b[2];
        #pragma unroll
        for (int i = 0; i < 4; ++i)
            a[i] = *(const f16x8*)&cur[(quad * 128 + wm + i * 16 + lq) * 8];
        #pragma unroll
        for (int j = 0; j < 2; ++j)
            b[j] = *(const f16x8*)&cur[4096 + (quad * 64 + wn + j * 16 + lq) * 8];
        #pragma unroll
        for (int i = 0; i < 4; ++i)
            #pragma unroll
            for (int j = 0; j < 2; ++j)
                acc[i][j] = __builtin_amdgcn_mfma_f32_16x16x32_f16(a[i], b[j], acc[i][j], 0, 0, 0);

        if (kt + 1 < 32) {
            _Float16* nxt = sm + ((kt + 1) & 1) * 6144;
            #pragma unroll
            for (int i = 0; i < 3; ++i) {
                const int c = c0 + i;
                _Float16* d = (c < 8) ? &nxt[c * 512] : &nxt[4096 + (c - 8) * 512];
                *(f16x8*)&d[lane * 8] = pf[i];
            }
        }
        __syncthreads();
    }

    #pragma unroll
    for (int jf = 0; jf < 2; ++jf) {
        const int col = nb * 64 + wn + jf * 16 + lq;
        const float bv = bias[col];
        #pragma unroll
        for (int i = 0; i < 4; ++i)
            #pragma unroll
            for (int r = 0; r < 4; ++r) {
                const int row = mb * 128 + wm + i * 16 + quad * 4 + r;
                out[(size_t)row * WIDTH + col] = acc[i][jf][r] + bv;
            }
    }
}

// ===========================================================================
extern "C" void kernel_launch(void* const* d_in, const int* in_sizes, int n_in,
                              void* d_out, int out_size, void* d_ws, size_t ws_size,
                              hipStream_t stream)
{
    const float* x      = (const float*)d_in[0];
    const float* w_qkv  = (const float*)d_in[1];
    const float* b_qkv  = (const float*)d_in[2];
    const float* w_proj = (const float*)d_in[3];
    const float* b_proj = (const float*)d_in[4];
    float* out = (float*)d_out;

    char* p = (char*)d_ws;
    size_t o = 0;
    __half* A1  = (__half*)(p + o); o += (size_t)MROWS * WIDTH * 2;
    __half* Bq  = (__half*)(p + o); o += (size_t)WIDTH * QKVD * 2;
    __half* Qg  = (__half*)(p + o); o += (size_t)MROWS * WIDTH * 2;
    __half* Kg  = (__half*)(p + o); o += (size_t)MROWS * WIDTH * 2;
    __half* Vtg = (__half*)(p + o); o += (size_t)MROWS * WIDTH * 2;
    __half* A2  = (__half*)(p + o); o += (size_t)MROWS * WIDTH * 2;
    __half* Bp  = (__half*)(p + o); o += (size_t)WIDTH * WIDTH * 2;

    split_all<<<dim3(2048), dim3(256), 0, stream>>>(x, w_qkv, w_proj, A1, Bq, Bp);

    gemm_qkv<<<dim3(24, 32), dim3(256), 0, stream>>>(A1, Bq, b_qkv, Qg, Kg, Vtg);

    attn_mfma13<<<dim3(1024), dim3(256), 0, stream>>>(Qg, Kg, Vtg, A2);

    gemm_proj<<<dim3(16, 32), dim3(256), 0, stream>>>(A2, Bp, b_proj, out);
}